// Round 4
// baseline (94.151 us; speedup 1.0000x reference)
//
#include <hip/hip_runtime.h>
#include <math.h>

#define IMG    224
#define NVIEWS 6
#define BATCH  16
#define NPTS   32768
#define PLANE  (IMG * IMG)       // 50176
#define NQUAD  4                 // row-quadrants per (b,v)
#define QROWS  56                // rows per quadrant tile
#define TILE_ELEMS (QROWS * IMG) // 12544 u32 = 50176 B dynamic LDS
#define NT     512
#define NWAVES (NT / 64)         // 8
#define QCAP   320               // per-wave queue entries (append<=256/group, qcnt<64 between groups)
#define NWG    (BATCH * NVIEWS * NQUAD) // 384  -> 2 WGs/CU on 256 CUs
#define KITERS (NPTS / (4 * NT))        // 16

typedef float fx4 __attribute__((ext_vector_type(4)));   // native vec for nontemporal

struct ViewTrig {
    float sa[NVIEWS], ca[NVIEWS], se[NVIEWS], ce[NVIEWS];
    float off0, off4;            // extreme splat offsets (footprint rectangle)
};

// fp32 ops with contraction OFF — these feed the pixel truncation and must
// round exactly like numpy's separate mul/add ufuncs.
__device__ __forceinline__ float fmul_(float a, float b) {
#pragma clang fp contract(off)
    return a * b;
}
__device__ __forceinline__ float fadd_(float a, float b) {
#pragma clang fp contract(off)
    return a + b;
}
__device__ __forceinline__ float fsub_(float a, float b) {
#pragma clang fp contract(off)
    return a - b;
}
// ((c + 1) * 0.5) * 223, truncate toward zero == astype(int32).
// (c+1)*0.5 is EXACT in fp32, so the two-step chain rounds exactly once on
// (c+1)*111.5 — identical to a single fmul by 111.5.
__device__ __forceinline__ int pix_(float c) {
    return (int)fmul_(fadd_(c, 1.0f), 111.5f);
}

// Order-preserving float->uint map (monotone over all finite floats).
// Any finite zf maps to a value > 0, so 0 is a safe "empty pixel" sentinel.
__device__ __forceinline__ unsigned fmap_(float f) {
    unsigned b = __float_as_uint(f);
    return b ^ ((unsigned)((int)b >> 31) | 0x80000000u);
}
__device__ __forceinline__ float fmap_inv_(unsigned u) {
    unsigned b = (u & 0x80000000u) ? (u ^ 0x80000000u) : ~u;
    return __uint_as_float(b);
}

__device__ __forceinline__ int lane_prefix_(unsigned long long m) {
    return __builtin_amdgcn_mbcnt_hi((unsigned)(m >> 32),
           __builtin_amdgcn_mbcnt_lo((unsigned)m, 0));
}

// ---------------------------------------------------------------------------
// Fused single-scan render with WAVE-PRIVATE LDS QUEUE compaction —
// QUADRANT-TILED for 2 WGs/CU.
//
// Rounds 2-3 post-mortem: two scan rewrites (center-splat, all-LDS dirty
// overlay) were neutral-to-negative vs the queue kernel -> the scan's LDS
// issue count is NOT the bottleneck. The shared structural cost is zero
// inter-WG overlap: 117KB LDS forced 1 WG/CU and 192 WGs idled 64 CUs,
// serializing scan -> reduce -> store-drain with nothing to hide them.
//
// This version keeps the round-1 queue algorithm verbatim but shrinks the
// tile to a 56-row quadrant: 50KB tile + 20KB queue -> 2 WGs/CU, 384 WGs,
// all CUs busy; one WG's epilogue HBM drain overlaps the other's scan VALU.
// (Each WG still scans all points: aggregate scan VALU doubles — accepted
// bet that render is stall-bound, not VALU-bound.)
// ---------------------------------------------------------------------------
__global__ __launch_bounds__(NT, 4) void render_kernel(
    const float* __restrict__ pts, float* __restrict__ out, ViewTrig vt)
{
    extern __shared__ __align__(16) unsigned tile[];
    __shared__ uint2 wq[NWAVES][QCAP];              // 20 KB static
    __shared__ float smin[NWAVES], smax[NWAVES];

    // XCD-aware decode: xcd = bid&7 -> batches {xcd, xcd+8} pin to one XCD L2
    const int bid  = blockIdx.x;
    const int xcd  = bid & 7;
    const int slot = bid >> 3;            // 0..47
    const int hi   = (slot >= 24) ? 1 : 0;
    const int b    = xcd + 8 * hi;
    const int vq   = slot - 24 * hi;      // 0..23
    const int v    = vq >> 2;
    const int q    = vq & 3;
    const int bv   = b * NVIEWS + v;
    const int row0 = q * QROWS;
    const int row1 = row0 + QROWS - 1;

    const float sa = vt.sa[v], ca = vt.ca[v], se = vt.se[v], ce = vt.ce[v];
    const float off0 = vt.off0, off4 = vt.off4;
    const float4* p4 = (const float4*)(pts + (size_t)b * NPTS * 3);

    const int lane = threadIdx.x & 63;
    const int wave = threadIdx.x >> 6;
    const int tid  = threadIdx.x;

    // zero tile (b128 stores)
    {
        int4* t4 = (int4*)tile;
        for (int i = tid; i < TILE_ELEMS / 4; i += NT)
            t4[i] = make_int4(0, 0, 0, 0);
    }
    __syncthreads();

    float zmin = INFINITY, zmax = -INFINITY;
    unsigned qcnt = 0;                    // wave-uniform queue fill

    // dense drain of 64 queue entries (all lanes useful)
    auto drain64 = [&]() {
        qcnt -= 64;
        const uint2 e = wq[wave][qcnt + lane];
        const unsigned fz = e.x, pk = e.y;
        const int cx0 = pk & 255;
        const int cx1 = (pk >> 8) & 255;
        const int r0 = max((int)((pk >> 16) & 255), row0) - row0;
        const int r1 = min((int)(pk >> 24), row1) - row0;
        #pragma unroll
        for (int dy = 0; dy < 3; ++dy) {
            const int ry = r0 + dy;
            const bool yok = (ry <= r1);
            #pragma unroll
            for (int dx = 0; dx < 3; ++dx) {
                const int cx = cx0 + dx;
                if (yok && (cx <= cx1)) atomicMax(&tile[ry * IMG + cx], fz);
            }
        }
    };

    auto do_point = [&](float x, float y, float z) {
        // strict fp32 chain -> pixel coordinates (bit-exact vs numpy)
        const float zr = fadd_(fmul_(x, sa), fmul_(z, ca));
        const float yr = fsub_(fmul_(y, ce), fmul_(zr, se));
        const float xr = fsub_(fmul_(x, ca), fmul_(z, sa));

        const int x0i = pix_(fadd_(xr, off0));
        const int x1i = pix_(fadd_(xr, off4));
        const int y0i = pix_(fadd_(yr, off0));
        const int y1i = pix_(fadd_(yr, off4));

        // relaxed depth (feeds minmax and the splat payload)
        const float zf = fmaf(zr, ce, y * se);
        zmin = fminf(zmin, zf);
        zmax = fmaxf(zmax, zf);

        const bool pred = (x1i >= 0) && (x0i <= IMG - 1) &&
                          (y1i >= row0) && (y0i <= row1);
        const unsigned long long m = __ballot(pred);
        if (pred) {
            // one-sided clamps: pred guarantees x0i<=223, x1i>=0 (monotone
            // pix => x1i>=x0i); y clamped against quadrant rows in drain.
            const int cx0 = max(x0i, 0);
            const int cx1 = min(x1i, IMG - 1);
            const int cy0 = max(y0i, 0);
            const int cy1 = min(y1i, IMG - 1);
            const unsigned pk = (unsigned)cx0 | ((unsigned)cx1 << 8) |
                                ((unsigned)cy0 << 16) | ((unsigned)cy1 << 24);
            wq[wave][qcnt + lane_prefix_(m)] = make_uint2(fmap_(zf), pk);
        }
        qcnt += (unsigned)__popcll(m);    // wave-uniform
    };

    // Software-pipelined scan: loads for iteration k+1 are issued before the
    // 4-point body + drains of iteration k.
    float4 A = p4[3 * tid + 0];
    float4 B = p4[3 * tid + 1];
    float4 C = p4[3 * tid + 2];
    #pragma unroll 4
    for (int k = 0; k < KITERS; ++k) {
        float4 An, Bn, Cn;
        if (k + 1 < KITERS) {
            const int g = tid + (k + 1) * NT;
            An = p4[3 * g + 0];
            Bn = p4[3 * g + 1];
            Cn = p4[3 * g + 2];
        }
        do_point(A.x, A.y, A.z);
        do_point(A.w, B.x, B.y);
        do_point(B.z, B.w, C.x);
        do_point(C.y, C.z, C.w);
        // group drain: queue holds < 64 + 4*64 = 320 <= QCAP
        while (qcnt >= 64) drain64();
        if (k + 1 < KITERS) { A = An; B = Bn; C = Cn; }
    }

    // final partial drain (< 64 entries)
    if (lane < (int)qcnt) {
        const uint2 e = wq[wave][lane];
        const unsigned fz = e.x, pk = e.y;
        const int cx0 = pk & 255;
        const int cx1 = (pk >> 8) & 255;
        const int r0 = max((int)((pk >> 16) & 255), row0) - row0;
        const int r1 = min((int)(pk >> 24), row1) - row0;
        #pragma unroll
        for (int dy = 0; dy < 3; ++dy) {
            const int ry = r0 + dy;
            const bool yok = (ry <= r1);
            #pragma unroll
            for (int dx = 0; dx < 3; ++dx) {
                const int cx = cx0 + dx;
                if (yok && (cx <= cx1)) atomicMax(&tile[ry * IMG + cx], fz);
            }
        }
    }

    // ---- block reduce zmin/zmax ----
    for (int o = 32; o > 0; o >>= 1) {
        zmin = fminf(zmin, __shfl_down(zmin, o, 64));
        zmax = fmaxf(zmax, __shfl_down(zmax, o, 64));
    }
    if (lane == 0) { smin[wave] = zmin; smax[wave] = zmax; }
    __syncthreads();   // also orders all LDS atomics before the epilogue
    if (threadIdx.x == 0) {
        float mn = smin[0], mx = smax[0];
        for (int w = 1; w < NWAVES; ++w) {
            mn = fminf(mn, smin[w]);
            mx = fmaxf(mx, smax[w]);
        }
        smin[0] = mn; smax[0] = mx;
    }
    __syncthreads();
    // feat = 0.3 + 0.7*(zf-zmin)/denom == zf*scale + bias  (err ~1e-6 << 2e-2)
    const float scale = 0.7f / ((smax[0] - smin[0]) + 1e-6f);
    const float bias  = 0.3f - smin[0] * scale;

    // ---- epilogue: tile -> feat -> channels 0,1,2 (non-temporal fx4) ----
    float* dst = out + ((size_t)bv * 3) * PLANE + (size_t)row0 * IMG;
    const uint4* src = (const uint4*)tile;
    for (int i = tid; i < TILE_ELEMS / 4; i += NT) {
        const uint4 u = src[i];
        fx4 f;
        f.x = (u.x == 0u) ? 0.0f : fmaf(fmap_inv_(u.x), scale, bias);
        f.y = (u.y == 0u) ? 0.0f : fmaf(fmap_inv_(u.y), scale, bias);
        f.z = (u.z == 0u) ? 0.0f : fmaf(fmap_inv_(u.z), scale, bias);
        f.w = (u.w == 0u) ? 0.0f : fmaf(fmap_inv_(u.w), scale, bias);
        #pragma unroll
        for (int c = 0; c < 3; ++c)
            __builtin_nontemporal_store(f, (fx4*)(dst + (size_t)c * PLANE) + i);
    }
}

extern "C" void kernel_launch(void* const* d_in, const int* in_sizes, int n_in,
                              void* d_out, int out_size, void* d_ws, size_t ws_size,
                              hipStream_t stream)
{
    const float* pts = (const float*)d_in[0];
    float* out = (float*)d_out;

    // fp32-faithful constants (JAX x32 semantics), same as the passing rounds.
    ViewTrig vt;
    const float d2r = (float)(M_PI / 180.0);
    const float el_deg[NVIEWS] = {0.0f, 30.0f, -30.0f, 0.0f, 0.0f, 0.0f};
    for (int v = 0; v < NVIEWS; ++v) {
        float a = (float)(60 * v) * d2r;
        float e = el_deg[v] * d2r;
        vt.sa[v] = (float)sin((double)a);
        vt.ca[v] = (float)cos((double)a);
        vt.se[v] = (float)sin((double)e);
        vt.ce[v] = (float)cos((double)e);
    }
    {
        const float s = (float)(2.0 / 224.0);  // linspace end points, exact in fp32
        vt.off0 = -s;
        vt.off4 = s;
    }

    // Dynamic LDS 50 KB (< 64 KB, attribute harmless). Graph-capture safe.
    (void)hipFuncSetAttribute(reinterpret_cast<const void*>(render_kernel),
                              hipFuncAttributeMaxDynamicSharedMemorySize,
                              TILE_ELEMS * (int)sizeof(int));

    render_kernel<<<NWG, NT, TILE_ELEMS * sizeof(int), stream>>>(pts, out, vt);
}

// Round 5
// 93.776 us; speedup vs baseline: 1.0040x; 1.0040x over previous
//
#include <hip/hip_runtime.h>
#include <math.h>

#define IMG    224
#define NVIEWS 6
#define BATCH  16
#define NPTS   32768
#define PLANE  (IMG * IMG)       // 50176
#define HROWS  112               // half-plane tile rows
#define TILE_ELEMS (HROWS * IMG) // 25088 u32 = 100352 B dynamic LDS

// ---- kernel 1 (transform + bin) ----
#define K1_NT    256
#define K1_CHUNK 8                              // chunks per (b,v); 4096 pts each
#define K1_NWG   (BATCH * NVIEWS * K1_CHUNK)    // 768 -> 3 WGs/CU
#define SEGCAP   1024                           // entries per wave-segment (= max pts/wave)
#define NSEG     (K1_CHUNK * 4)                 // 32 segments per bin

// ---- kernel 2 (splat + write) ----
#define K2_NT    1024
#define K2_NWG   (BATCH * NVIEWS * 2)           // 192

// ---- workspace layout (bytes) ----
// counts : [192 bins][32 segs] u32          @ 0       (24576 B)
// minmax : [96 bv][32 segs] uint2           @ 24576   (24576 B)  {max fmap(zf), max fmap(-zf)}
// bins   : [192 bins][32 segs][1024] uint2  @ 65536   (48 MiB)
#define WS_MM_OFF   24576
#define WS_BIN_OFF  65536

typedef float fx4 __attribute__((ext_vector_type(4)));

struct ViewTrig {
    float sa[NVIEWS], ca[NVIEWS], se[NVIEWS], ce[NVIEWS];
    float off0, off4;
};

// fp32 ops with contraction OFF — these feed the pixel truncation and must
// round exactly like numpy's separate mul/add ufuncs.
__device__ __forceinline__ float fmul_(float a, float b) {
#pragma clang fp contract(off)
    return a * b;
}
__device__ __forceinline__ float fadd_(float a, float b) {
#pragma clang fp contract(off)
    return a + b;
}
__device__ __forceinline__ float fsub_(float a, float b) {
#pragma clang fp contract(off)
    return a - b;
}
// ((c+1)*0.5)*223 trunc == (c+1)*111.5 trunc ((c+1)*0.5 exact in fp32).
__device__ __forceinline__ int pix_(float c) {
    return (int)fmul_(fadd_(c, 1.0f), 111.5f);
}

// Order-preserving float->uint map; finite f -> value > 0 (0 = empty sentinel).
__device__ __forceinline__ unsigned fmap_(float f) {
    unsigned b = __float_as_uint(f);
    return b ^ ((unsigned)((int)b >> 31) | 0x80000000u);
}
__device__ __forceinline__ float fmap_inv_(unsigned u) {
    unsigned b = (u & 0x80000000u) ? (u ^ 0x80000000u) : ~u;
    return __uint_as_float(b);
}

__device__ __forceinline__ int lane_prefix_(unsigned long long m) {
    return __builtin_amdgcn_mbcnt_hi((unsigned)(m >> 32),
           __builtin_amdgcn_mbcnt_lo((unsigned)m, 0));
}

// ---------------------------------------------------------------------------
// Kernel 1: transform each point ONCE per view (3.1M transforms vs 6.3M in
// the fused kernel), emit wave-compacted (fmap(zf), box) entries into
// deterministic per-wave global segments — zero atomics, zero barriers,
// nothing needs pre-zeroing (counts/minmax written unconditionally).
// WG = (b, v, chunk of 4096 points); 4 waves; 16 points/thread.
// ---------------------------------------------------------------------------
__global__ __launch_bounds__(K1_NT, 3) void transform_kernel(
    const float* __restrict__ pts, unsigned* __restrict__ ws, ViewTrig vt)
{
    const int bid   = blockIdx.x;
    const int chunk = bid & (K1_CHUNK - 1);
    const int v     = (bid >> 3) % NVIEWS;
    const int b     = bid / (K1_CHUNK * NVIEWS);
    const int bv    = b * NVIEWS + v;

    const float sa = vt.sa[v], ca = vt.ca[v], se = vt.se[v], ce = vt.ce[v];
    const float off0 = vt.off0, off4 = vt.off4;
    const float4* p4 = (const float4*)(pts + (size_t)b * NPTS * 3);

    const int tid = threadIdx.x, lane = tid & 63, wave = tid >> 6;
    const int segi = chunk * 4 + wave;                 // 0..31 within bin

    unsigned* counts = ws;
    uint2* minmax = (uint2*)((char*)ws + WS_MM_OFF);
    uint2* bins   = (uint2*)((char*)ws + WS_BIN_OFF);
    uint2* seg0 = bins + ((size_t)((bv * 2 + 0) * NSEG + segi)) * SEGCAP;
    uint2* seg1 = bins + ((size_t)((bv * 2 + 1) * NSEG + segi)) * SEGCAP;

    unsigned q0 = 0, q1 = 0;              // wave-uniform segment fills
    float zmin = INFINITY, zmax = -INFINITY;

    auto do_point = [&](float x, float y, float z) {
        // strict fp32 chain -> pixel coordinates (bit-exact vs numpy)
        const float zr = fadd_(fmul_(x, sa), fmul_(z, ca));
        const float yr = fsub_(fmul_(y, ce), fmul_(zr, se));
        const float xr = fsub_(fmul_(x, ca), fmul_(z, sa));

        const int x0i = pix_(fadd_(xr, off0));
        const int x1i = pix_(fadd_(xr, off4));
        const int y0i = pix_(fadd_(yr, off0));
        const int y1i = pix_(fadd_(yr, off4));

        // relaxed depth (same formula as all passing rounds)
        const float zf = fmaf(zr, ce, y * se);
        zmin = fminf(zmin, zf);
        zmax = fmaxf(zmax, zf);

        const bool okx = (x1i >= 0) && (x0i <= IMG - 1);
        const bool ok0 = okx && (y1i >= 0)     && (y0i <= HROWS - 1);
        const bool ok1 = okx && (y1i >= HROWS) && (y0i <= IMG - 1);

        const int cx0 = max(x0i, 0);
        const int cx1 = min(x1i, IMG - 1);
        const int cy0 = max(y0i, 0);
        const int cy1 = min(y1i, IMG - 1);
        const unsigned pk = (unsigned)cx0 | ((unsigned)cx1 << 8) |
                            ((unsigned)cy0 << 16) | ((unsigned)cy1 << 24);
        const unsigned fz = fmap_(zf);

        {   // half 0
            const unsigned long long m = __ballot(ok0);
            if (ok0) seg0[q0 + lane_prefix_(m)] = make_uint2(fz, pk);
            q0 += (unsigned)__popcll(m);
        }
        {   // half 1
            const unsigned long long m = __ballot(ok1);
            if (ok1) seg1[q1 + lane_prefix_(m)] = make_uint2(fz, pk);
            q1 += (unsigned)__popcll(m);
        }
    };

    // chunk covers point groups [chunk*1024, chunk*1024+1024); 4 groups/thread
    #pragma unroll
    for (int kk = 0; kk < 4; ++kk) {
        const int g = chunk * 1024 + kk * K1_NT + tid;   // 4-point group
        const float4 A = p4[3 * g + 0];
        const float4 B = p4[3 * g + 1];
        const float4 C = p4[3 * g + 2];
        do_point(A.x, A.y, A.z);
        do_point(A.w, B.x, B.y);
        do_point(B.z, B.w, C.x);
        do_point(C.y, C.z, C.w);
    }

    // wave-reduce minmax; lane 0 publishes counts + minmax (unconditional)
    for (int o = 32; o > 0; o >>= 1) {
        zmin = fminf(zmin, __shfl_down(zmin, o, 64));
        zmax = fmaxf(zmax, __shfl_down(zmax, o, 64));
    }
    if (lane == 0) {
        counts[(bv * 2 + 0) * NSEG + segi] = q0;
        counts[(bv * 2 + 1) * NSEG + segi] = q1;
        minmax[bv * NSEG + segi] = make_uint2(fmap_(zmax), fmap_(-zmin));
    }
}

// ---------------------------------------------------------------------------
// Kernel 2: per (b,v,half) WG — prefix the 32 segment counts, splat entries
// into the LDS tile (9 predicated atomics per entry, exactly round-1 drain
// semantics), then the strict epilogue. No scan, no z-reduce.
// ---------------------------------------------------------------------------
__global__ __launch_bounds__(K2_NT, 1) void splat_kernel(
    const unsigned* __restrict__ ws, float* __restrict__ out)
{
    extern __shared__ __align__(16) unsigned tile[];
    __shared__ unsigned pref[NSEG + 1];
    __shared__ float sScale, sBias;

    // XCD-aware decode (identical to the fused kernel)
    const int bid  = blockIdx.x;
    const int xcd  = bid & 7;
    const int slot = bid >> 3;            // 0..23
    const int hi   = (slot >= 12) ? 1 : 0;
    const int b    = xcd + 8 * hi;
    const int vh   = slot - 12 * hi;
    const int v    = vh >> 1;
    const int h    = vh & 1;
    const int bv   = b * NVIEWS + v;
    const int bvh  = bv * 2 + h;
    const int row0 = h * HROWS;
    const int row1 = row0 + HROWS - 1;

    const int tid = threadIdx.x, lane = tid & 63, wave = tid >> 6;

    const unsigned* counts = ws;
    const uint2* minmax = (const uint2*)((const char*)ws + WS_MM_OFF);
    const uint2* binb   = (const uint2*)((const char*)ws + WS_BIN_OFF)
                        + (size_t)bvh * NSEG * SEGCAP;

    // zero tile; wave 0 concurrently builds prefix + scale/bias
    {
        int4* t4 = (int4*)tile;
        for (int i = tid; i < TILE_ELEMS / 4; i += K2_NT)
            t4[i] = make_int4(0, 0, 0, 0);
    }
    if (wave == 0) {
        unsigned c = (lane < NSEG) ? counts[bvh * NSEG + lane] : 0u;
        unsigned inc = c;
        #pragma unroll
        for (int o = 1; o < NSEG; o <<= 1) {
            unsigned t = __shfl_up(inc, o, 64);
            if (lane >= o) inc += t;
        }
        if (lane < NSEG) pref[lane + 1] = inc;
        if (lane == 0)   pref[0] = 0;

        uint2 mm = (lane < NSEG) ? minmax[bv * NSEG + lane] : make_uint2(0u, 0u);
        for (int o = 32; o > 0; o >>= 1) {
            mm.x = max(mm.x, __shfl_down(mm.x, o, 64));
            mm.y = max(mm.y, __shfl_down(mm.y, o, 64));
        }
        if (lane == 0) {
            const float mx = fmap_inv_(mm.x);
            const float mn = -fmap_inv_(mm.y);
            const float scale = 0.7f / ((mx - mn) + 1e-6f);
            sScale = scale;
            sBias  = 0.3f - mn * scale;
        }
    }
    __syncthreads();

    // splat all entries (binary-search segment indirection)
    const unsigned n = pref[NSEG];
    for (unsigned e = tid; e < n; e += K2_NT) {
        int s = 0;
        #pragma unroll
        for (int st = 16; st >= 1; st >>= 1)
            if (pref[s + st] <= e) s += st;
        const uint2 ent = binb[(size_t)s * SEGCAP + (e - pref[s])];
        const unsigned fz = ent.x, pk = ent.y;
        const int cx0 = pk & 255;
        const int cx1 = (pk >> 8) & 255;
        const int r0 = max((int)((pk >> 16) & 255), row0) - row0;
        const int r1 = min((int)(pk >> 24), row1) - row0;
        #pragma unroll
        for (int dy = 0; dy < 3; ++dy) {
            const int ry = r0 + dy;
            const bool yok = (ry <= r1);
            #pragma unroll
            for (int dx = 0; dx < 3; ++dx) {
                const int cx = cx0 + dx;
                if (yok && (cx <= cx1)) atomicMax(&tile[ry * IMG + cx], fz);
            }
        }
    }
    __syncthreads();

    const float scale = sScale, bias = sBias;

    // epilogue: tile -> feat -> channels 0,1,2 (non-temporal fx4)
    float* dst = out + ((size_t)bv * 3) * PLANE + (size_t)row0 * IMG;
    const uint4* src = (const uint4*)tile;
    for (int i = tid; i < TILE_ELEMS / 4; i += K2_NT) {
        const uint4 u = src[i];
        fx4 f;
        f.x = (u.x == 0u) ? 0.0f : fmaf(fmap_inv_(u.x), scale, bias);
        f.y = (u.y == 0u) ? 0.0f : fmaf(fmap_inv_(u.y), scale, bias);
        f.z = (u.z == 0u) ? 0.0f : fmaf(fmap_inv_(u.z), scale, bias);
        f.w = (u.w == 0u) ? 0.0f : fmaf(fmap_inv_(u.w), scale, bias);
        #pragma unroll
        for (int c = 0; c < 3; ++c)
            __builtin_nontemporal_store(f, (fx4*)(dst + (size_t)c * PLANE) + i);
    }
}

extern "C" void kernel_launch(void* const* d_in, const int* in_sizes, int n_in,
                              void* d_out, int out_size, void* d_ws, size_t ws_size,
                              hipStream_t stream)
{
    const float* pts = (const float*)d_in[0];
    float* out = (float*)d_out;
    unsigned* ws = (unsigned*)d_ws;

    ViewTrig vt;
    const float d2r = (float)(M_PI / 180.0);
    const float el_deg[NVIEWS] = {0.0f, 30.0f, -30.0f, 0.0f, 0.0f, 0.0f};
    for (int v = 0; v < NVIEWS; ++v) {
        float a = (float)(60 * v) * d2r;
        float e = el_deg[v] * d2r;
        vt.sa[v] = (float)sin((double)a);
        vt.ca[v] = (float)cos((double)a);
        vt.se[v] = (float)sin((double)e);
        vt.ce[v] = (float)cos((double)e);
    }
    {
        const float s = (float)(2.0 / 224.0);
        vt.off0 = -s;
        vt.off4 = s;
    }

    // splat kernel needs 100 KB dynamic LDS (>64 KB opt-in). Graph-safe.
    (void)hipFuncSetAttribute(reinterpret_cast<const void*>(splat_kernel),
                              hipFuncAttributeMaxDynamicSharedMemorySize,
                              TILE_ELEMS * (int)sizeof(int));

    transform_kernel<<<K1_NWG, K1_NT, 0, stream>>>(pts, ws, vt);
    splat_kernel<<<K2_NWG, K2_NT, TILE_ELEMS * sizeof(int), stream>>>(ws, out);
}

// Round 6
// 92.507 us; speedup vs baseline: 1.0178x; 1.0137x over previous
//
#include <hip/hip_runtime.h>
#include <math.h>

#define IMG    224
#define NVIEWS 6
#define BATCH  16
#define NPTS   32768
#define PLANE  (IMG * IMG)       // 50176

// ---- kernel 1 (transform + quadrant-bin) ----
#define K1_NT    256
#define K1_CHUNK 8                              // chunks per (b,v); 4096 pts each
#define K1_NWG   (BATCH * NVIEWS * K1_CHUNK)    // 768 -> 3 WGs/CU
#define SEGCAP   1024                           // entries per wave-segment (= max pts/wave)
#define NSEG     (K1_CHUNK * 4)                 // 32 segments per bin
#define NQUAD    4                              // 56-row quadrants

// ---- kernel 2 (octant splat + write) ----
#define K2_NT    512
#define OROWS    28                             // octant tile rows
#define OTILE    (OROWS * IMG)                  // 6272 u32 = 25088 B LDS
#define K2_NWG   (BATCH * NVIEWS * 8)           // 768 -> 3 WGs/CU co-resident

// ---- workspace layout (bytes); ws is 256 MiB ----
// counts : [96 bv][4 quad][32 seg] u32              @ 0      (49152 B)
// minmax : [96 bv][32 seg] uint2                    @ 49152  (24576 B)
// bins   : [96 bv][4 quad][32 seg][1024] uint2      @ 73728  (100.7 MB)
#define WS_MM_OFF   49152
#define WS_BIN_OFF  73728

typedef float fx4 __attribute__((ext_vector_type(4)));

struct ViewTrig {
    float sa[NVIEWS], ca[NVIEWS], se[NVIEWS], ce[NVIEWS];
    float off0, off4;
};

// fp32 ops with contraction OFF — these feed the pixel truncation and must
// round exactly like numpy's separate mul/add ufuncs.
__device__ __forceinline__ float fmul_(float a, float b) {
#pragma clang fp contract(off)
    return a * b;
}
__device__ __forceinline__ float fadd_(float a, float b) {
#pragma clang fp contract(off)
    return a + b;
}
__device__ __forceinline__ float fsub_(float a, float b) {
#pragma clang fp contract(off)
    return a - b;
}
// ((c+1)*0.5)*223 trunc == (c+1)*111.5 trunc ((c+1)*0.5 exact in fp32).
__device__ __forceinline__ int pix_(float c) {
    return (int)fmul_(fadd_(c, 1.0f), 111.5f);
}

// Order-preserving float->uint map; finite f -> value > 0 (0 = empty sentinel).
__device__ __forceinline__ unsigned fmap_(float f) {
    unsigned b = __float_as_uint(f);
    return b ^ ((unsigned)((int)b >> 31) | 0x80000000u);
}
__device__ __forceinline__ float fmap_inv_(unsigned u) {
    unsigned b = (u & 0x80000000u) ? (u ^ 0x80000000u) : ~u;
    return __uint_as_float(b);
}

__device__ __forceinline__ int lane_prefix_(unsigned long long m) {
    return __builtin_amdgcn_mbcnt_hi((unsigned)(m >> 32),
           __builtin_amdgcn_mbcnt_lo((unsigned)m, 0));
}

// ---------------------------------------------------------------------------
// Kernel 1: transform each point ONCE per view, emit wave-compacted
// (fmap(zf), box) entries into deterministic per-wave global segments,
// binned by 56-row QUADRANT (boxes span <=3 rows -> ~2.7% straddlers
// duplicated into two quadrants). Zero atomics, zero barriers, nothing
// needs pre-zeroing (counts/minmax written unconditionally).
// WG = (b, v, chunk of 4096 points); 4 waves; 16 points/thread.
// ---------------------------------------------------------------------------
__global__ __launch_bounds__(K1_NT, 3) void transform_kernel(
    const float* __restrict__ pts, unsigned* __restrict__ ws, ViewTrig vt)
{
    const int bid   = blockIdx.x;
    const int chunk = bid & (K1_CHUNK - 1);
    const int v     = (bid >> 3) % NVIEWS;
    const int b     = bid / (K1_CHUNK * NVIEWS);
    const int bv    = b * NVIEWS + v;

    const float sa = vt.sa[v], ca = vt.ca[v], se = vt.se[v], ce = vt.ce[v];
    const float off0 = vt.off0, off4 = vt.off4;
    const float4* p4 = (const float4*)(pts + (size_t)b * NPTS * 3);

    const int tid = threadIdx.x, lane = tid & 63, wave = tid >> 6;
    const int segi = chunk * 4 + wave;                 // 0..31 within bin

    unsigned* counts = ws;
    uint2* minmax = (uint2*)((char*)ws + WS_MM_OFF);
    uint2* bins   = (uint2*)((char*)ws + WS_BIN_OFF);
    uint2* seg[NQUAD];
    #pragma unroll
    for (int q = 0; q < NQUAD; ++q)
        seg[q] = bins + ((size_t)((bv * NQUAD + q) * NSEG + segi)) * SEGCAP;

    unsigned qn[NQUAD] = {0u, 0u, 0u, 0u};    // wave-uniform fills
    float zmin = INFINITY, zmax = -INFINITY;

    auto do_point = [&](float x, float y, float z) {
        // strict fp32 chain -> pixel coordinates (bit-exact vs numpy)
        const float zr = fadd_(fmul_(x, sa), fmul_(z, ca));
        const float yr = fsub_(fmul_(y, ce), fmul_(zr, se));
        const float xr = fsub_(fmul_(x, ca), fmul_(z, sa));

        const int x0i = pix_(fadd_(xr, off0));
        const int x1i = pix_(fadd_(xr, off4));
        const int y0i = pix_(fadd_(yr, off0));
        const int y1i = pix_(fadd_(yr, off4));

        // relaxed depth (same formula as all passing rounds)
        const float zf = fmaf(zr, ce, y * se);
        zmin = fminf(zmin, zf);
        zmax = fmaxf(zmax, zf);

        const bool okx = (x1i >= 0) && (x0i <= IMG - 1);

        const int cx0 = max(x0i, 0);
        const int cx1 = min(x1i, IMG - 1);
        const int cy0 = max(y0i, 0);
        const int cy1 = min(y1i, IMG - 1);
        const unsigned pk = (unsigned)cx0 | ((unsigned)cx1 << 8) |
                            ((unsigned)cy0 << 16) | ((unsigned)cy1 << 24);
        const unsigned fz = fmap_(zf);

        #pragma unroll
        for (int q = 0; q < NQUAD; ++q) {
            const bool ok = okx && (y1i >= 56 * q) && (y0i <= 56 * q + 55);
            const unsigned long long m = __ballot(ok);
            if (ok) seg[q][qn[q] + lane_prefix_(m)] = make_uint2(fz, pk);
            qn[q] += (unsigned)__popcll(m);
        }
    };

    // chunk covers point groups [chunk*1024, chunk*1024+1024); 4 groups/thread
    #pragma unroll
    for (int kk = 0; kk < 4; ++kk) {
        const int g = chunk * 1024 + kk * K1_NT + tid;   // 4-point group
        const float4 A = p4[3 * g + 0];
        const float4 B = p4[3 * g + 1];
        const float4 C = p4[3 * g + 2];
        do_point(A.x, A.y, A.z);
        do_point(A.w, B.x, B.y);
        do_point(B.z, B.w, C.x);
        do_point(C.y, C.z, C.w);
    }

    // wave-reduce minmax; lane 0 publishes counts + minmax (unconditional)
    for (int o = 32; o > 0; o >>= 1) {
        zmin = fminf(zmin, __shfl_down(zmin, o, 64));
        zmax = fmaxf(zmax, __shfl_down(zmax, o, 64));
    }
    if (lane == 0) {
        #pragma unroll
        for (int q = 0; q < NQUAD; ++q)
            counts[(bv * NQUAD + q) * NSEG + segi] = qn[q];
        minmax[bv * NSEG + segi] = make_uint2(fmap_(zmax), fmap_(-zmin));
    }
}

// ---------------------------------------------------------------------------
// Kernel 2: per (b,v,octant) WG — 28-row tile (25 KB LDS), 768 WGs, 3/CU
// co-resident so one WG's epilogue HBM drain overlaps another's splat.
// Reads the parent quadrant bin, filters entries by row overlap, splats
// (round-1 drain semantics), then the strict epilogue. Consecutive bids
// sharing a quadrant bin map to the same XCD (oct bit above the xcd bits)
// for L2 reuse of the bin data.
// ---------------------------------------------------------------------------
__global__ __launch_bounds__(K2_NT, 6) void splat_kernel(
    const unsigned* __restrict__ ws, float* __restrict__ out)
{
    extern __shared__ __align__(16) unsigned tile[];
    __shared__ unsigned pref[NSEG + 1];
    __shared__ float sScale, sBias;

    const int bid  = blockIdx.x;
    const int xcd  = bid & 7;
    const int slot = bid >> 3;            // 0..95
    const int oct  = slot & 1;            // octant within quadrant
    const int rest = slot >> 1;           // 0..47
    const int hi   = (rest >= 24) ? 1 : 0;
    const int sub  = rest - 24 * hi;      // 0..23
    const int v    = sub >> 2;
    const int quad = sub & 3;
    const int b    = xcd + 8 * hi;
    const int bv   = b * NVIEWS + v;
    const int bin  = bv * NQUAD + quad;
    const int row0g = quad * 56 + oct * OROWS;   // global first row of tile
    const int row1g = row0g + OROWS - 1;

    const int tid = threadIdx.x, lane = tid & 63, wave = tid >> 6;

    const unsigned* counts = ws;
    const uint2* minmax = (const uint2*)((const char*)ws + WS_MM_OFF);
    const uint2* binb   = (const uint2*)((const char*)ws + WS_BIN_OFF)
                        + (size_t)bin * NSEG * SEGCAP;

    // zero tile; wave 0 concurrently builds prefix + scale/bias
    {
        int4* t4 = (int4*)tile;
        for (int i = tid; i < OTILE / 4; i += K2_NT)
            t4[i] = make_int4(0, 0, 0, 0);
    }
    if (wave == 0) {
        unsigned c = (lane < NSEG) ? counts[bin * NSEG + lane] : 0u;
        unsigned inc = c;
        #pragma unroll
        for (int o = 1; o < NSEG; o <<= 1) {
            unsigned t = __shfl_up(inc, o, 64);
            if (lane >= o) inc += t;
        }
        if (lane < NSEG) pref[lane + 1] = inc;
        if (lane == 0)   pref[0] = 0;

        uint2 mm = (lane < NSEG) ? minmax[bv * NSEG + lane] : make_uint2(0u, 0u);
        for (int o = 32; o > 0; o >>= 1) {
            mm.x = max(mm.x, __shfl_down(mm.x, o, 64));
            mm.y = max(mm.y, __shfl_down(mm.y, o, 64));
        }
        if (lane == 0) {
            const float mx = fmap_inv_(mm.x);
            const float mn = -fmap_inv_(mm.y);
            const float scale = 0.7f / ((mx - mn) + 1e-6f);
            sScale = scale;
            sBias  = 0.3f - mn * scale;
        }
    }
    __syncthreads();

    // splat entries overlapping this octant (binary-search segment lookup)
    const unsigned n = pref[NSEG];
    for (unsigned e = tid; e < n; e += K2_NT) {
        int s = 0;
        #pragma unroll
        for (int st = 16; st >= 1; st >>= 1)
            if (pref[s + st] <= e) s += st;
        const uint2 ent = binb[(size_t)s * SEGCAP + (e - pref[s])];
        const unsigned fz = ent.x, pk = ent.y;
        const int r0 = max((int)((pk >> 16) & 255), row0g);
        const int r1 = min((int)(pk >> 24), row1g);
        if (r0 > r1) continue;                      // other octant's rows
        const int cx0 = pk & 255;
        const int cx1 = (pk >> 8) & 255;
        const int rl = r0 - row0g, rh = r1 - row0g;
        #pragma unroll
        for (int dy = 0; dy < 3; ++dy) {
            const int ry = rl + dy;
            const bool yok = (ry <= rh);
            #pragma unroll
            for (int dx = 0; dx < 3; ++dx) {
                const int cx = cx0 + dx;
                if (yok && (cx <= cx1)) atomicMax(&tile[ry * IMG + cx], fz);
            }
        }
    }
    __syncthreads();

    const float scale = sScale, bias = sBias;

    // epilogue: tile -> feat -> channels 0,1,2 (non-temporal fx4)
    float* dst = out + ((size_t)bv * 3) * PLANE + (size_t)row0g * IMG;
    const uint4* src = (const uint4*)tile;
    for (int i = tid; i < OTILE / 4; i += K2_NT) {
        const uint4 u = src[i];
        fx4 f;
        f.x = (u.x == 0u) ? 0.0f : fmaf(fmap_inv_(u.x), scale, bias);
        f.y = (u.y == 0u) ? 0.0f : fmaf(fmap_inv_(u.y), scale, bias);
        f.z = (u.z == 0u) ? 0.0f : fmaf(fmap_inv_(u.z), scale, bias);
        f.w = (u.w == 0u) ? 0.0f : fmaf(fmap_inv_(u.w), scale, bias);
        #pragma unroll
        for (int c = 0; c < 3; ++c)
            __builtin_nontemporal_store(f, (fx4*)(dst + (size_t)c * PLANE) + i);
    }
}

extern "C" void kernel_launch(void* const* d_in, const int* in_sizes, int n_in,
                              void* d_out, int out_size, void* d_ws, size_t ws_size,
                              hipStream_t stream)
{
    const float* pts = (const float*)d_in[0];
    float* out = (float*)d_out;
    unsigned* ws = (unsigned*)d_ws;

    ViewTrig vt;
    const float d2r = (float)(M_PI / 180.0);
    const float el_deg[NVIEWS] = {0.0f, 30.0f, -30.0f, 0.0f, 0.0f, 0.0f};
    for (int v = 0; v < NVIEWS; ++v) {
        float a = (float)(60 * v) * d2r;
        float e = el_deg[v] * d2r;
        vt.sa[v] = (float)sin((double)a);
        vt.ca[v] = (float)cos((double)a);
        vt.se[v] = (float)sin((double)e);
        vt.ce[v] = (float)cos((double)e);
    }
    {
        const float s = (float)(2.0 / 224.0);
        vt.off0 = -s;
        vt.off4 = s;
    }

    transform_kernel<<<K1_NWG, K1_NT, 0, stream>>>(pts, ws, vt);
    splat_kernel<<<K2_NWG, K2_NT, OTILE * sizeof(unsigned), stream>>>(ws, out);
}

// Round 7
// 87.463 us; speedup vs baseline: 1.0765x; 1.0577x over previous
//
#include <hip/hip_runtime.h>
#include <math.h>
#include <type_traits>

#define IMG    224
#define NVIEWS 6
#define BATCH  16
#define NPTS   32768
#define PLANE  (IMG * IMG)       // 50176
#define HROWS  112               // half-plane tile
#define TILE_ELEMS (HROWS * IMG) // 25088 u32 = 100352 B dynamic LDS
#define NT     1024
#define NWAVES (NT / 64)         // 16
#define QCAP   320               // per-wave queue entries (append<=256/group, qcnt<64 between groups)
#define NWG    (BATCH * NVIEWS * 2) // 192
#define KITERS (NPTS / (4 * NT))    // 8

typedef float fx4 __attribute__((ext_vector_type(4)));   // native vec for nontemporal

struct ViewTrig {
    float sa[NVIEWS], ca[NVIEWS], se[NVIEWS], ce[NVIEWS];
    float off0, off4;            // extreme splat offsets (footprint rectangle)
};

// fp32 ops with contraction OFF — these feed the pixel truncation and must
// round exactly like numpy's separate mul/add ufuncs.
__device__ __forceinline__ float fmul_(float a, float b) {
#pragma clang fp contract(off)
    return a * b;
}
__device__ __forceinline__ float fadd_(float a, float b) {
#pragma clang fp contract(off)
    return a + b;
}
__device__ __forceinline__ float fsub_(float a, float b) {
#pragma clang fp contract(off)
    return a - b;
}
// ((c + 1) * 0.5) * 223, truncate toward zero == astype(int32).
// (c+1)*0.5 is EXACT in fp32, so the two-step chain rounds exactly once on
// (c+1)*111.5 — identical to a single fmul by 111.5.
__device__ __forceinline__ int pix_(float c) {
    return (int)fmul_(fadd_(c, 1.0f), 111.5f);
}

// Order-preserving float->uint map (monotone over all finite floats).
// Any finite zf maps to a value > 0, so 0 is a safe "empty pixel" sentinel.
__device__ __forceinline__ unsigned fmap_(float f) {
    unsigned b = __float_as_uint(f);
    return b ^ ((unsigned)((int)b >> 31) | 0x80000000u);
}
__device__ __forceinline__ float fmap_inv_(unsigned u) {
    unsigned b = (u & 0x80000000u) ? (u ^ 0x80000000u) : ~u;
    return __uint_as_float(b);
}

__device__ __forceinline__ int lane_prefix_(unsigned long long m) {
    return __builtin_amdgcn_mbcnt_hi((unsigned)(m >> 32),
           __builtin_amdgcn_mbcnt_lo((unsigned)m, 0));
}

// ---------------------------------------------------------------------------
// Fused single-scan render with WAVE-PRIVATE LDS QUEUE compaction (round-1
// structure — the measured best across 6 structural variants).
//
// This revision adds the last cheap levers:
//  * EL0 specialization: views with se==0 (4 of 6 -> 2/3 of WGs) have
//    yr = y and zf = zr BIT-EXACTLY (y*1=y; y -+-0 = y feeding fadd with a
//    nonzero offset; zf sign-of-zero differences only reorder exact ties
//    of +-0 depths, value-identical through feat). Scan loop is duplicated
//    at compile time via integral_constant, cutting ~5 VALU/point.
//  * First point loads issued BEFORE the tile-zero barrier (latency hidden
//    under the zeroing).
// ---------------------------------------------------------------------------
__global__ __launch_bounds__(NT, 4) void render_kernel(
    const float* __restrict__ pts, float* __restrict__ out, ViewTrig vt)
{
    extern __shared__ __align__(16) unsigned tile[];
    __shared__ uint2 wq[NWAVES][QCAP];              // 40 KB static
    __shared__ float smin[NWAVES], smax[NWAVES];

    // XCD-aware decode: xcd = bid&7 -> batches {xcd, xcd+8} pin to one XCD L2
    const int bid  = blockIdx.x;
    const int xcd  = bid & 7;
    const int slot = bid >> 3;            // 0..23
    const int hi   = (slot >= 12) ? 1 : 0;
    const int b    = xcd + 8 * hi;
    const int vh   = slot - 12 * hi;
    const int v    = vh >> 1;
    const int h    = vh & 1;
    const int bv   = b * NVIEWS + v;
    const int row0 = h * HROWS;
    const int row1 = row0 + HROWS - 1;

    const float sa = vt.sa[v], ca = vt.ca[v], se = vt.se[v], ce = vt.ce[v];
    const float off0 = vt.off0, off4 = vt.off4;
    const float4* p4 = (const float4*)(pts + (size_t)b * NPTS * 3);

    const int lane = threadIdx.x & 63;
    const int wave = threadIdx.x >> 6;
    const int tid  = threadIdx.x;

    // issue the first point loads before the zero/barrier (latency hidden)
    float4 A = p4[3 * tid + 0];
    float4 B = p4[3 * tid + 1];
    float4 C = p4[3 * tid + 2];

    // zero tile (b128 stores)
    {
        int4* t4 = (int4*)tile;
        for (int i = tid; i < TILE_ELEMS / 4; i += NT)
            t4[i] = make_int4(0, 0, 0, 0);
    }
    __syncthreads();

    float zmin = INFINITY, zmax = -INFINITY;
    unsigned qcnt = 0;                    // wave-uniform queue fill

    // dense drain of 64 queue entries (all lanes useful)
    auto drain64 = [&]() {
        qcnt -= 64;
        const uint2 e = wq[wave][qcnt + lane];
        const unsigned fz = e.x, pk = e.y;
        const int cx0 = pk & 255;
        const int cx1 = (pk >> 8) & 255;
        const int r0 = max((int)((pk >> 16) & 255), row0) - row0;
        const int r1 = min((int)(pk >> 24), row1) - row0;
        #pragma unroll
        for (int dy = 0; dy < 3; ++dy) {
            const int ry = r0 + dy;
            const bool yok = (ry <= r1);
            #pragma unroll
            for (int dx = 0; dx < 3; ++dx) {
                const int cx = cx0 + dx;
                if (yok && (cx <= cx1)) atomicMax(&tile[ry * IMG + cx], fz);
            }
        }
    };

    auto do_point = [&](auto el0c, float x, float y, float z) {
        constexpr bool EL0 = decltype(el0c)::value;
        // strict fp32 chain -> pixel coordinates (bit-exact vs numpy)
        const float zr = fadd_(fmul_(x, sa), fmul_(z, ca));
        const float yr = EL0 ? y : fsub_(fmul_(y, ce), fmul_(zr, se));
        const float xr = fsub_(fmul_(x, ca), fmul_(z, sa));

        const int x0i = pix_(fadd_(xr, off0));
        const int x1i = pix_(fadd_(xr, off4));
        const int y0i = pix_(fadd_(yr, off0));
        const int y1i = pix_(fadd_(yr, off4));

        // relaxed depth (feeds minmax and the splat payload)
        const float zf = EL0 ? zr : fmaf(zr, ce, y * se);
        zmin = fminf(zmin, zf);
        zmax = fmaxf(zmax, zf);

        const bool pred = (x1i >= 0) && (x0i <= IMG - 1) &&
                          (y1i >= row0) && (y0i <= row1);
        const unsigned long long m = __ballot(pred);
        if (pred) {
            // one-sided clamps where pred guarantees the other side
            const int cx0 = max(x0i, 0);
            const int cx1 = min(x1i, IMG - 1);
            const int cy0 = max(y0i, 0);
            const int cy1 = min(y1i, IMG - 1);
            const unsigned pk = (unsigned)cx0 | ((unsigned)cx1 << 8) |
                                ((unsigned)cy0 << 16) | ((unsigned)cy1 << 24);
            wq[wave][qcnt + lane_prefix_(m)] = make_uint2(fmap_(zf), pk);
        }
        qcnt += (unsigned)__popcll(m);    // wave-uniform
    };

    // Software-pipelined scan: loads for iteration k+1 are issued before the
    // 4-point body + drains of iteration k. Loop duplicated per EL0 variant.
    auto scan = [&](auto el0c) {
        #pragma unroll
        for (int k = 0; k < KITERS; ++k) {
            float4 An, Bn, Cn;
            if (k + 1 < KITERS) {
                const int g = tid + (k + 1) * NT;
                An = p4[3 * g + 0];
                Bn = p4[3 * g + 1];
                Cn = p4[3 * g + 2];
            }
            do_point(el0c, A.x, A.y, A.z);
            do_point(el0c, A.w, B.x, B.y);
            do_point(el0c, B.z, B.w, C.x);
            do_point(el0c, C.y, C.z, C.w);
            // group drain: queue holds < 64 + 4*64 = 320 <= QCAP
            while (qcnt >= 64) drain64();
            if (k + 1 < KITERS) { A = An; B = Bn; C = Cn; }
        }
    };
    if (se == 0.0f && ce == 1.0f) scan(std::true_type{});
    else                          scan(std::false_type{});

    // final partial drain (< 64 entries)
    if (lane < (int)qcnt) {
        const uint2 e = wq[wave][lane];
        const unsigned fz = e.x, pk = e.y;
        const int cx0 = pk & 255;
        const int cx1 = (pk >> 8) & 255;
        const int r0 = max((int)((pk >> 16) & 255), row0) - row0;
        const int r1 = min((int)(pk >> 24), row1) - row0;
        #pragma unroll
        for (int dy = 0; dy < 3; ++dy) {
            const int ry = r0 + dy;
            const bool yok = (ry <= r1);
            #pragma unroll
            for (int dx = 0; dx < 3; ++dx) {
                const int cx = cx0 + dx;
                if (yok && (cx <= cx1)) atomicMax(&tile[ry * IMG + cx], fz);
            }
        }
    }

    // ---- block reduce zmin/zmax ----
    for (int o = 32; o > 0; o >>= 1) {
        zmin = fminf(zmin, __shfl_down(zmin, o, 64));
        zmax = fmaxf(zmax, __shfl_down(zmax, o, 64));
    }
    if (lane == 0) { smin[wave] = zmin; smax[wave] = zmax; }
    __syncthreads();   // also orders all LDS atomics before the epilogue
    if (threadIdx.x == 0) {
        float mn = smin[0], mx = smax[0];
        for (int w = 1; w < NWAVES; ++w) {
            mn = fminf(mn, smin[w]);
            mx = fmaxf(mx, smax[w]);
        }
        smin[0] = mn; smax[0] = mx;
    }
    __syncthreads();
    // feat = 0.3 + 0.7*(zf-zmin)/denom == zf*scale + bias  (err ~1e-6 << 2e-2)
    const float scale = 0.7f / ((smax[0] - smin[0]) + 1e-6f);
    const float bias  = 0.3f - smin[0] * scale;

    // ---- epilogue: tile -> feat -> channels 0,1,2 (non-temporal fx4) ----
    float* dst = out + ((size_t)bv * 3) * PLANE + (size_t)row0 * IMG;
    const uint4* src = (const uint4*)tile;
    for (int i = tid; i < TILE_ELEMS / 4; i += NT) {
        const uint4 u = src[i];
        fx4 f;
        f.x = (u.x == 0u) ? 0.0f : fmaf(fmap_inv_(u.x), scale, bias);
        f.y = (u.y == 0u) ? 0.0f : fmaf(fmap_inv_(u.y), scale, bias);
        f.z = (u.z == 0u) ? 0.0f : fmaf(fmap_inv_(u.z), scale, bias);
        f.w = (u.w == 0u) ? 0.0f : fmaf(fmap_inv_(u.w), scale, bias);
        #pragma unroll
        for (int c = 0; c < 3; ++c)
            __builtin_nontemporal_store(f, (fx4*)(dst + (size_t)c * PLANE) + i);
    }
}

extern "C" void kernel_launch(void* const* d_in, const int* in_sizes, int n_in,
                              void* d_out, int out_size, void* d_ws, size_t ws_size,
                              hipStream_t stream)
{
    const float* pts = (const float*)d_in[0];
    float* out = (float*)d_out;

    // fp32-faithful constants (JAX x32 semantics), same as the passing rounds.
    ViewTrig vt;
    const float d2r = (float)(M_PI / 180.0);
    const float el_deg[NVIEWS] = {0.0f, 30.0f, -30.0f, 0.0f, 0.0f, 0.0f};
    for (int v = 0; v < NVIEWS; ++v) {
        float a = (float)(60 * v) * d2r;
        float e = el_deg[v] * d2r;
        vt.sa[v] = (float)sin((double)a);
        vt.ca[v] = (float)cos((double)a);
        vt.se[v] = (float)sin((double)e);
        vt.ce[v] = (float)cos((double)e);
    }
    {
        const float s = (float)(2.0 / 224.0);  // linspace end points, exact in fp32
        vt.off0 = -s;
        vt.off4 = s;
    }

    // Opt in to >64KB dynamic LDS (160 KiB/CU on gfx950). Graph-capture safe.
    (void)hipFuncSetAttribute(reinterpret_cast<const void*>(render_kernel),
                              hipFuncAttributeMaxDynamicSharedMemorySize,
                              TILE_ELEMS * (int)sizeof(int));

    render_kernel<<<NWG, NT, TILE_ELEMS * sizeof(int), stream>>>(pts, out, vt);
}